// Round 3
// baseline (700.098 us; speedup 1.0000x reference)
//
#include <hip/hip_runtime.h>
#include <math.h>

#define TT 512
#define BB 64
#define DD 1024
#define NN 64
#define PC 256   // 4*NN projection columns

__device__ __forceinline__ float fast_sigmoid(float x) {
    float e = __builtin_amdgcn_exp2f(x * -1.442695041f);
    return __builtin_amdgcn_rcpf(1.0f + e);
}

// cross-lane add helpers: butterfly sum over 16-lane groups.
// xor1 = quad_perm[1,0,3,2] (0xB1), xor2 = quad_perm[2,3,0,1] (0x4E),
// xor4 via ds_swizzle BitMode (0x101F); final cross-half stage via DPP
// row_mirror (0x140, lane^=15 within the 16-lane row) — after the first
// three stages each 8-half is uniform, so any cross-half perm completes it.
// (Bug fixed: 0x141 row_half_mirror stays in the same half -> doubled half-sum.)
template<int C>
__device__ __forceinline__ float dpp_mov(float x) {
    return __int_as_float(__builtin_amdgcn_update_dpp(
        0, __float_as_int(x), C, 0xF, 0xF, true));
}
__device__ __forceinline__ float red16(float x) {
    x += dpp_mov<0xB1>(x);                                   // xor 1
    x += dpp_mov<0x4E>(x);                                   // xor 2
    x += __int_as_float(__builtin_amdgcn_ds_swizzle(
             __float_as_int(x), 0x101F));                    // xor 4
    x += dpp_mov<0x140>(x);                                  // row_mirror: cross-half
    return x;                                                // all 16 lanes have sum
}

// ---------------- Projection GEMM ----------------
// P[r][n] = sum_d X[r][d] * W[n][d],  X:[32768,1024], W:[256,1024], P:[32768,256]
// Tile: 64 rows x 256 cols per block, BK=16. 512 blocks, 256 threads.
__global__ __launch_bounds__(256) void proj_gemm(
    const float* __restrict__ X,
    const float* __restrict__ W,
    float* __restrict__ P)
{
    __shared__ float Xs[16][68];    // [k][row], padded
    __shared__ float Ws[16][260];   // [k][col], padded

    const int t    = threadIdx.x;
    const int row0 = blockIdx.x * 64;
    const int m4   = (t & 15) * 4;   // output row group
    const int n16  = (t >> 4) * 16;  // output col group
    const int lr   = t >> 2;         // load row 0..63
    const int lk   = (t & 3) * 4;    // load k offset

    float acc[4][16];
#pragma unroll
    for (int m = 0; m < 4; ++m)
#pragma unroll
        for (int n = 0; n < 16; ++n) acc[m][n] = 0.f;

    const float* Xp = X + (long)(row0 + lr) * DD + lk;
    const float* Wp = W + (long)lr * DD + lk;

    for (int k0 = 0; k0 < DD; k0 += 16) {
        float4 xv = *(const float4*)(Xp + k0);
        float4 wv[4];
#pragma unroll
        for (int u = 0; u < 4; ++u)
            wv[u] = *(const float4*)(Wp + (long)u * 64 * DD + k0);

        __syncthreads();   // protect previous iteration's LDS reads
        Xs[lk+0][lr] = xv.x; Xs[lk+1][lr] = xv.y;
        Xs[lk+2][lr] = xv.z; Xs[lk+3][lr] = xv.w;
#pragma unroll
        for (int u = 0; u < 4; ++u) {
            const int wr = lr + 64*u;
            Ws[lk+0][wr] = wv[u].x; Ws[lk+1][wr] = wv[u].y;
            Ws[lk+2][wr] = wv[u].z; Ws[lk+3][wr] = wv[u].w;
        }
        __syncthreads();

#pragma unroll
        for (int k = 0; k < 16; ++k) {
            float4 a  = *(const float4*)&Xs[k][m4];
            float4 b0 = *(const float4*)&Ws[k][n16];
            float4 b1 = *(const float4*)&Ws[k][n16+4];
            float4 b2 = *(const float4*)&Ws[k][n16+8];
            float4 b3 = *(const float4*)&Ws[k][n16+12];
            const float av[4]  = {a.x, a.y, a.z, a.w};
            const float bv[16] = {b0.x,b0.y,b0.z,b0.w, b1.x,b1.y,b1.z,b1.w,
                                  b2.x,b2.y,b2.z,b2.w, b3.x,b3.y,b3.z,b3.w};
#pragma unroll
            for (int m = 0; m < 4; ++m)
#pragma unroll
                for (int n = 0; n < 16; ++n)
                    acc[m][n] = fmaf(av[m], bv[n], acc[m][n]);
        }
    }

#pragma unroll
    for (int m = 0; m < 4; ++m) {
        float* Cp = P + (long)(row0 + m4 + m) * PC + n16;
#pragma unroll
        for (int g = 0; g < 4; ++g) {
            float4 o = make_float4(acc[m][4*g], acc[m][4*g+1],
                                   acc[m][4*g+2], acc[m][4*g+3]);
            *(float4*)(Cp + 4*g) = o;
        }
    }
}

// ---------------- Recurrent gated scan (barrier-free, row-parallel) ----------------
// Given normalized k_n, m_n (which depend only on proj), every (batch,row)
// recurrence is independent. Wave layout: 4 rows/wave, 16 lanes/row,
// 4 columns/lane. Row dots via 4-stage butterfly in the 16-lane group.
// No LDS, no __syncthreads. 256 blocks x 256 threads = 1024 waves.
__global__ __launch_bounds__(256) void gate_scan(
    const float* __restrict__ P,    // [T, B, 256] = [k|v|q|m]
    const float* __restrict__ S0,   // [B, 64, 64]
    const float* __restrict__ M0,
    const float* __restrict__ B_S,  // [64, 64]
    const float* __restrict__ B_M,
    float* __restrict__ out)        // [T*B*64] ++ [B*4096] ++ [B*4096]
{
    const int bid  = blockIdx.x;          // 0..255
    const int w    = threadIdx.x >> 6;    // wave in block 0..3
    const int lane = threadIdx.x & 63;
    const int xcd  = bid & 7;
    const int yy   = bid >> 3;            // 0..31
    const int b    = 8 * xcd + (yy >> 2); // batch 0..63 (4 blocks/batch share XCD)
    const int rg   = (yy & 3) * 4 + w;    // row-group 0..15
    const int rs   = lane >> 4;           // row within group 0..3
    const int li   = lane & 15;           // lane within row
    const int i    = rg * 4 + rs;         // matrix row 0..63
    const int j0   = li * 4;              // first owned column

    // per-lane state: 4 columns of row i of S and M, plus bias rows
    float S[4], M[4], BS[4], BM[4];
    {
        const float4 s4 = *(const float4*)(S0  + (long)b*4096 + i*64 + j0);
        const float4 m4 = *(const float4*)(M0  + (long)b*4096 + i*64 + j0);
        const float4 e4 = *(const float4*)(B_S + i*64 + j0);
        const float4 f4 = *(const float4*)(B_M + i*64 + j0);
        S[0]=s4.x; S[1]=s4.y; S[2]=s4.z; S[3]=s4.w;
        M[0]=m4.x; M[1]=m4.y; M[2]=m4.z; M[3]=m4.w;
        BS[0]=e4.x; BS[1]=e4.y; BS[2]=e4.z; BS[3]=e4.w;
        BM[0]=f4.x; BM[1]=f4.y; BM[2]=f4.z; BM[3]=f4.w;
    }

    const float* Pb = P + (long)b * PC;
    const long   st = (long)BB * PC;      // per-step stride in floats

    // current-step inputs
    float4 k4 = *(const float4*)(Pb + j0);
    float4 q4 = *(const float4*)(Pb + 128 + j0);
    float4 m4 = *(const float4*)(Pb + 192 + j0);
    float  vv = Pb[64 + i];

    for (int t = 0; t < TT; ++t) {
        // prefetch next step (state-independent addresses -> hides HBM latency)
        const long nb = (long)((t + 1 < TT) ? t + 1 : t) * st;
        const float4 k4n = *(const float4*)(Pb + nb + j0);
        const float4 q4n = *(const float4*)(Pb + nb + 128 + j0);
        const float4 m4n = *(const float4*)(Pb + nb + 192 + j0);
        const float  vvn = Pb[nb + 64 + i];

        // ---- normalize k and m (identical across the 4 row-groups; free) ----
        float kk = k4.x*k4.x + k4.y*k4.y + k4.z*k4.z + k4.w*k4.w;
        float mm = m4.x*m4.x + m4.y*m4.y + m4.z*m4.z + m4.w*m4.w;
        kk = red16(kk);
        mm = red16(mm);
        const float kinv = __builtin_amdgcn_rcpf(sqrtf(kk) + 1e-6f);
        const float minv = __builtin_amdgcn_rcpf(sqrtf(mm) + 1e-6f);
        const float kn[4] = {k4.x*kinv, k4.y*kinv, k4.z*kinv, k4.w*kinv};
        const float mn[4] = {m4.x*minv, m4.y*minv, m4.z*minv, m4.w*minv};

        // ---- row dots with old S, old M against k_n ----
        float sk = S[0]*kn[0] + S[1]*kn[1] + S[2]*kn[2] + S[3]*kn[3];
        float mk = M[0]*kn[0] + M[1]*kn[1] + M[2]*kn[2] + M[3]*kn[3];
        sk = red16(sk);
        mk = red16(mk);
        const float sd = vv - sk;            // s_delta[i]

        // ---- S update ----
#pragma unroll
        for (int e = 0; e < 4; ++e) {
            const float g = fast_sigmoid(fmaf(mk, kn[e], M[e] + BS[e]));
            S[e] = fmaf(g, S[e], sd * kn[e]);
        }

        // ---- row dots: new S, old M against m_n ----
        float sm = S[0]*mn[0] + S[1]*mn[1] + S[2]*mn[2] + S[3]*mn[3];
        float mv = M[0]*mn[0] + M[1]*mn[1] + M[2]*mn[2] + M[3]*mn[3];
        sm = red16(sm);
        mv = red16(mv);
        const float md = sd - mv;            // m_delta[i]

        // ---- M update ----
#pragma unroll
        for (int e = 0; e < 4; ++e) {
            const float g = fast_sigmoid(fmaf(sm, mn[e], S[e] + BM[e]));
            M[e] = fmaf(g, M[e], md * mn[e]);
        }

        // ---- readout: Sq * silu(Sq) ----
        float sq = S[0]*q4.x + S[1]*q4.y + S[2]*q4.z + S[3]*q4.w;
        sq = red16(sq);
        if (li == 0)
            out[((long)t * BB + b) * NN + i] = sq * sq * fast_sigmoid(sq);

        k4 = k4n; q4 = q4n; m4 = m4n; vv = vvn;
    }

    // final S, M
    float* So = out + (long)TT*BB*NN + (long)b*4096 + i*64 + j0;
    float* Mo = So + (long)BB*4096;
    *(float4*)So = make_float4(S[0], S[1], S[2], S[3]);
    *(float4*)Mo = make_float4(M[0], M[1], M[2], M[3]);
}

extern "C" void kernel_launch(void* const* d_in, const int* in_sizes, int n_in,
                              void* d_out, int out_size, void* d_ws, size_t ws_size,
                              hipStream_t stream) {
    const float* x    = (const float*)d_in[0];  // [512,64,1024]
    const float* S0   = (const float*)d_in[1];  // [64,64,64]
    const float* M0   = (const float*)d_in[2];
    const float* W    = (const float*)d_in[3];  // [256,1024]
    const float* B_S  = (const float*)d_in[4];  // [64,64]
    const float* B_M  = (const float*)d_in[5];
    float* out  = (float*)d_out;
    float* proj = (float*)d_ws;                 // 512*64*256*4 = 32 MB

    proj_gemm<<<512, 256, 0, stream>>>(x, W, proj);
    gate_scan<<<256, 256, 0, stream>>>(proj, S0, M0, B_S, B_M, out);
}

// Round 4
// 596.795 us; speedup vs baseline: 1.1731x; 1.1731x over previous
//
#include <hip/hip_runtime.h>
#include <math.h>

#define TT 512
#define BB 64
#define DD 1024
#define NN 64
#define PC 256   // 4*NN projection columns

__device__ __forceinline__ float fast_sigmoid(float x) {
    float e = __builtin_amdgcn_exp2f(x * -1.442695041f);
    return __builtin_amdgcn_rcpf(1.0f + e);
}

template<int C>
__device__ __forceinline__ float dpp_mov(float x) {
    return __int_as_float(__builtin_amdgcn_update_dpp(
        0, __float_as_int(x), C, 0xF, 0xF, true));
}
template<int P>
__device__ __forceinline__ float swz(float x) {
    return __int_as_float(__builtin_amdgcn_ds_swizzle(__float_as_int(x), P));
}
// butterfly sum across each 32-lane half (all 32 lanes get the sum)
__device__ __forceinline__ float red32(float x) {
    x += dpp_mov<0xB1>(x);     // xor 1 (quad_perm [1,0,3,2])
    x += dpp_mov<0x4E>(x);     // xor 2 (quad_perm [2,3,0,1])
    x += swz<0x101F>(x);       // xor 4
    x += swz<0x201F>(x);       // xor 8
    x += swz<0x401F>(x);       // xor 16
    return x;
}

// ---------------- Projection GEMM (fp32, dbuf, 1 barrier/tile, fused norm) ----
// P[r][n] = sum_d X[r][d]*W[n][d];  X:[32768,1024], W:[256,1024], P:[32768,256]
// Block: 64 rows x 256 cols, BK=16, 512 blocks x 256 thr (2 blocks/CU).
// Wave w owns cols [64w,64w+64): wave0 = k-section, wave3 = m-section ->
// row-normalization of k and m fused into the epilogue (scan reads kn/mn).
__global__ __launch_bounds__(256, 2) void proj_gemm(
    const float* __restrict__ X,
    const float* __restrict__ W,
    float* __restrict__ P)
{
    __shared__ float Xs[2][16][68];    // [buf][k][row], padded
    __shared__ float Ws[2][16][260];   // [buf][k][col], padded

    const int t    = threadIdx.x;
    const int row0 = blockIdx.x * 64;
    const int m4   = (t & 15) * 4;   // output row group
    const int n16  = (t >> 4) * 16;  // output col group
    const int lr   = t >> 2;         // load row 0..63
    const int lk   = (t & 3) * 4;    // load k offset

    float2 acc[4][8];
#pragma unroll
    for (int m = 0; m < 4; ++m)
#pragma unroll
        for (int j = 0; j < 8; ++j) acc[m][j] = make_float2(0.f, 0.f);

    const float* Xp = X + (long)(row0 + lr) * DD + lk;
    const float* Wp = W + (long)lr * DD + lk;

    // prologue: tile 0 into regs
    float4 xv  = *(const float4*)(Xp);
    float4 wv0 = *(const float4*)(Wp);
    float4 wv1 = *(const float4*)(Wp + 64 * DD);
    float4 wv2 = *(const float4*)(Wp + 128 * DD);
    float4 wv3 = *(const float4*)(Wp + 192 * DD);

    for (int kt = 0; kt < 64; ++kt) {
        const int cur = kt & 1;
        // publish tile kt (only racing work is compute(kt-1) on the OTHER buf)
        Xs[cur][lk+0][lr] = xv.x; Xs[cur][lk+1][lr] = xv.y;
        Xs[cur][lk+2][lr] = xv.z; Xs[cur][lk+3][lr] = xv.w;
        Ws[cur][lk+0][lr]       = wv0.x; Ws[cur][lk+1][lr]       = wv0.y;
        Ws[cur][lk+2][lr]       = wv0.z; Ws[cur][lk+3][lr]       = wv0.w;
        Ws[cur][lk+0][lr + 64]  = wv1.x; Ws[cur][lk+1][lr + 64]  = wv1.y;
        Ws[cur][lk+2][lr + 64]  = wv1.z; Ws[cur][lk+3][lr + 64]  = wv1.w;
        Ws[cur][lk+0][lr + 128] = wv2.x; Ws[cur][lk+1][lr + 128] = wv2.y;
        Ws[cur][lk+2][lr + 128] = wv2.z; Ws[cur][lk+3][lr + 128] = wv2.w;
        Ws[cur][lk+0][lr + 192] = wv3.x; Ws[cur][lk+1][lr + 192] = wv3.y;
        Ws[cur][lk+2][lr + 192] = wv3.z; Ws[cur][lk+3][lr + 192] = wv3.w;

        // issue next tile's loads (in flight across barrier + compute)
        if (kt < 63) {
            const int k0 = (kt + 1) * 16;
            xv  = *(const float4*)(Xp + k0);
            wv0 = *(const float4*)(Wp + k0);
            wv1 = *(const float4*)(Wp + 64 * DD + k0);
            wv2 = *(const float4*)(Wp + 128 * DD + k0);
            wv3 = *(const float4*)(Wp + 192 * DD + k0);
        }
        __syncthreads();   // single barrier per tile

#pragma unroll
        for (int k = 0; k < 16; ++k) {
            const float4 a4 = *(const float4*)&Xs[cur][k][m4];
            const float4 b0 = *(const float4*)&Ws[cur][k][n16];
            const float4 b1 = *(const float4*)&Ws[cur][k][n16 + 4];
            const float4 b2 = *(const float4*)&Ws[cur][k][n16 + 8];
            const float4 b3 = *(const float4*)&Ws[cur][k][n16 + 12];
            const float av[4]  = {a4.x, a4.y, a4.z, a4.w};
            const float bv[16] = {b0.x,b0.y,b0.z,b0.w, b1.x,b1.y,b1.z,b1.w,
                                  b2.x,b2.y,b2.z,b2.w, b3.x,b3.y,b3.z,b3.w};
#pragma unroll
            for (int m = 0; m < 4; ++m)
#pragma unroll
                for (int j = 0; j < 8; ++j) {
                    acc[m][j].x = fmaf(av[m], bv[2*j],     acc[m][j].x);
                    acc[m][j].y = fmaf(av[m], bv[2*j + 1], acc[m][j].y);
                }
        }
    }

    // ---- fused normalization: wave0 (k-cols) and wave3 (m-cols) ----
    const int wid = t >> 6;
    if (wid == 0 || wid == 3) {
#pragma unroll
        for (int m = 0; m < 4; ++m) {
            float p = 0.f;
#pragma unroll
            for (int j = 0; j < 8; ++j)
                p += acc[m][j].x * acc[m][j].x + acc[m][j].y * acc[m][j].y;
            p += swz<0x401F>(p);       // xor16: lanes l <-> l^16
            p += __shfl_xor(p, 32);    // cross-half
            const float inv = __builtin_amdgcn_rcpf(sqrtf(p) + 1e-6f);
#pragma unroll
            for (int j = 0; j < 8; ++j) { acc[m][j].x *= inv; acc[m][j].y *= inv; }
        }
    }

#pragma unroll
    for (int m = 0; m < 4; ++m) {
        float* Cp = P + (long)(row0 + m4 + m) * PC + n16;
#pragma unroll
        for (int g = 0; g < 4; ++g) {
            float4 o = make_float4(acc[m][2*g].x, acc[m][2*g].y,
                                   acc[m][2*g+1].x, acc[m][2*g+1].y);
            *(float4*)(Cp + 4*g) = o;
        }
    }
}

// ---------------- Recurrent gated scan (barrier-free, 32 lanes/row) ----------
// 4096 (batch,row) sequences, each independent given pre-normalized kn/mn.
// Wave: 2 rows, 32 lanes/row, 2 cols/lane -> 2048 waves = 2 waves/SIMD.
// Row dots via 5-stage butterfly within 32-lane halves. No LDS, no barriers.
// All 8 blocks of a batch share an XCD (bid%8 heuristic) for L2 locality.
__global__ __launch_bounds__(256) void gate_scan(
    const float* __restrict__ P,    // [T, B, 256] = [kn | v | q | mn]
    const float* __restrict__ S0,   // [B, 64, 64]
    const float* __restrict__ M0,
    const float* __restrict__ B_S,  // [64, 64]
    const float* __restrict__ B_M,
    float* __restrict__ out)        // [T*B*64] ++ [B*4096] ++ [B*4096]
{
    const int bid  = blockIdx.x;            // 0..511
    const int grp  = bid >> 3;
    const int b    = (bid & 7) * 8 + (grp >> 3);   // batch 0..63
    const int sub  = grp & 7;                      // block-within-batch
    const int w    = threadIdx.x >> 6;
    const int lane = threadIdx.x & 63;
    const int half = lane >> 5;
    const int li   = lane & 31;
    const int j0   = li * 2;                       // owned columns j0, j0+1
    const int r    = sub * 8 + w * 2 + half;       // matrix row 0..63

    float2 S2, M2, BS2, BM2;
    S2  = *(const float2*)(S0  + (long)b * 4096 + r * 64 + j0);
    M2  = *(const float2*)(M0  + (long)b * 4096 + r * 64 + j0);
    BS2 = *(const float2*)(B_S + r * 64 + j0);
    BM2 = *(const float2*)(B_M + r * 64 + j0);

    const float* Pb = P + (long)b * PC;
    const long   st = (long)BB * PC;    // per-step stride (floats)

    float2 kn = *(const float2*)(Pb + j0);
    float2 q2 = *(const float2*)(Pb + 128 + j0);
    float2 mn = *(const float2*)(Pb + 192 + j0);
    float  vv = Pb[64 + r];

    for (int t = 0; t < TT; ++t) {
        const long nb = (long)((t + 1 < TT) ? t + 1 : t) * st;
        const float2 knn = *(const float2*)(Pb + nb + j0);
        const float2 qn  = *(const float2*)(Pb + nb + 128 + j0);
        const float2 mnn = *(const float2*)(Pb + nb + 192 + j0);
        const float  vvn = Pb[nb + 64 + r];

        // dots with old S, old M against kn
        float sk = fmaf(S2.y, kn.y, S2.x * kn.x);
        float mk = fmaf(M2.y, kn.y, M2.x * kn.x);
        sk = red32(sk);
        mk = red32(mk);
        const float sd = vv - sk;              // s_delta[r]

        // S update (gate from old M)
        {
            const float g0 = fast_sigmoid(fmaf(mk, kn.x, M2.x + BS2.x));
            const float g1 = fast_sigmoid(fmaf(mk, kn.y, M2.y + BS2.y));
            S2.x = fmaf(g0, S2.x, sd * kn.x);
            S2.y = fmaf(g1, S2.y, sd * kn.y);
        }

        // dots: new S, old M against mn
        float sm = fmaf(S2.y, mn.y, S2.x * mn.x);
        float mv = fmaf(M2.y, mn.y, M2.x * mn.x);
        sm = red32(sm);
        mv = red32(mv);
        const float md = sd - mv;              // m_delta[r]

        // M update (gate from new S)
        {
            const float g0 = fast_sigmoid(fmaf(sm, mn.x, S2.x + BM2.x));
            const float g1 = fast_sigmoid(fmaf(sm, mn.y, S2.y + BM2.y));
            M2.x = fmaf(g0, M2.x, md * mn.x);
            M2.y = fmaf(g1, M2.y, md * mn.y);
        }

        // readout: Sq * silu(Sq), q NOT normalized
        float sq = fmaf(S2.y, q2.y, S2.x * q2.x);
        sq = red32(sq);
        if (li == 0)
            out[((long)t * BB + b) * NN + r] = sq * sq * fast_sigmoid(sq);

        kn = knn; q2 = qn; mn = mnn; vv = vvn;
    }

    float* So = out + (long)TT * BB * NN + (long)b * 4096 + r * 64 + j0;
    float* Mo = So + (long)BB * 4096;
    *(float2*)So = S2;
    *(float2*)Mo = M2;
}

extern "C" void kernel_launch(void* const* d_in, const int* in_sizes, int n_in,
                              void* d_out, int out_size, void* d_ws, size_t ws_size,
                              hipStream_t stream) {
    const float* x    = (const float*)d_in[0];  // [512,64,1024]
    const float* S0   = (const float*)d_in[1];  // [64,64,64]
    const float* M0   = (const float*)d_in[2];
    const float* W    = (const float*)d_in[3];  // [256,1024]
    const float* B_S  = (const float*)d_in[4];  // [64,64]
    const float* B_M  = (const float*)d_in[5];
    float* out  = (float*)d_out;
    float* proj = (float*)d_ws;                 // 512*64*256*4 = 32 MB

    proj_gemm<<<512, 256, 0, stream>>>(x, W, proj);
    gate_scan<<<512, 256, 0, stream>>>(proj, S0, M0, B_S, B_M, out);
}

// Round 8
// 568.623 us; speedup vs baseline: 1.2312x; 1.0495x over previous
//
#include <hip/hip_runtime.h>
#include <math.h>

#define TT 512
#define BB 64
#define DD 1024
#define NN 64
#define PC 256   // 4*NN projection columns

__device__ __forceinline__ float fast_sigmoid(float x) {
    float e = __builtin_amdgcn_exp2f(x * -1.442695041f);
    return __builtin_amdgcn_rcpf(1.0f + e);
}

template<int C>
__device__ __forceinline__ float dpp_mov(float x) {
    return __int_as_float(__builtin_amdgcn_update_dpp(
        0, __float_as_int(x), C, 0xF, 0xF, true));
}
template<int P>
__device__ __forceinline__ float swz(float x) {
    return __int_as_float(__builtin_amdgcn_ds_swizzle(__float_as_int(x), P));
}
// Butterfly sum across each 32-lane half; only ONE LDS-pipe op (xor16).
// s1 xor1 (quad_perm), s2 xor2 (quad_perm) -> quads uniform;
// s3 row_mirror (quad q += q^3); s4 row_ror:8 (quad q += pair q^2,q^1);
// s5 xor16 via ds_swizzle.
__device__ __forceinline__ float red32(float x) {
    x += dpp_mov<0xB1>(x);     // xor 1
    x += dpp_mov<0x4E>(x);     // xor 2
    x += dpp_mov<0x140>(x);    // row_mirror
    x += dpp_mov<0x128>(x);    // row_ror:8
    x += swz<0x401F>(x);       // xor 16
    return x;
}

// ---------------- Projection GEMM (fp32, 128x128 tile, 8x8/thread) ----------
// P[r][n] = sum_d X[r][d]*W[n][d];  X:[32768,1024], W:[256,1024], P:[32768,256]
// 512 blocks (256 rowblks x 2 colblks) x 256 thr, 2 blocks/CU.
// A-tile uses interleaved column layout pc(row) so both A b128 reads are
// bank-conflict-free. lgkm-only barrier keeps prefetch loads in flight.
// Row-normalization of k (cols 0-63, even blocks) and m (cols 192-255, odd
// blocks) fused into the epilogue via LDS scratch.
__global__ __launch_bounds__(256, 2) void proj_gemm(
    const float* __restrict__ X,
    const float* __restrict__ W,
    float* __restrict__ P)
{
    __shared__ float Xs[2][16][132];
    __shared__ float Ws[2][16][132];

    const int t      = threadIdx.x;
    const int rowblk = blockIdx.x >> 1;
    const int colblk = blockIdx.x & 1;
    const int row0   = rowblk * 128;
    const int col0   = colblk * 128;
    const int rg     = t & 15;       // row group (8 rows)
    const int cg     = t >> 4;       // col group (8 cols)
    const int m8     = rg * 8;
    const int n8     = cg * 8;

    // loader mapping: ids t and t+256 -> (row = id>>2, k-offset = (id&3)*4)
    const int lrow0 = t >> 2;
    const int lrow1 = lrow0 + 64;
    const int lkg   = (t & 3) * 4;

    const float* Xp0 = X + (long)(row0 + lrow0) * DD + lkg;
    const float* Xp1 = X + (long)(row0 + lrow1) * DD + lkg;
    const float* Wp0 = W + (long)(col0 + lrow0) * DD + lkg;
    const float* Wp1 = W + (long)(col0 + lrow1) * DD + lkg;

    // interleaved phys column for X rows: rows 8g..8g+3 -> g*4.., 8g+4..7 -> 64+g*4..
    const int pc0 = ((lrow0 & 4) << 4) + ((lrow0 >> 3) << 2) + (lrow0 & 3);
    const int pc1 = ((lrow1 & 4) << 4) + ((lrow1 >> 3) << 2) + (lrow1 & 3);

    float acc[8][8];
#pragma unroll
    for (int u = 0; u < 8; ++u)
#pragma unroll
        for (int v = 0; v < 8; ++v) acc[u][v] = 0.f;

    float4 x0 = *(const float4*)(Xp0);
    float4 x1 = *(const float4*)(Xp1);
    float4 w0 = *(const float4*)(Wp0);
    float4 w1 = *(const float4*)(Wp1);

    for (int kt = 0; kt < 64; ++kt) {
        const int cur = kt & 1;
        // publish tile kt (prev loads auto-waited via vmcnt on first use)
        {
            const float xa0[4] = {x0.x, x0.y, x0.z, x0.w};
            const float xa1[4] = {x1.x, x1.y, x1.z, x1.w};
            const float wa0[4] = {w0.x, w0.y, w0.z, w0.w};
            const float wa1[4] = {w1.x, w1.y, w1.z, w1.w};
#pragma unroll
            for (int f = 0; f < 4; ++f) {
                Xs[cur][lkg + f][pc0]   = xa0[f];
                Xs[cur][lkg + f][pc1]   = xa1[f];
                Ws[cur][lkg + f][lrow0] = wa0[f];
                Ws[cur][lkg + f][lrow1] = wa1[f];
            }
        }
        // issue next tile's loads (stay in flight across barrier + compute)
        if (kt < 63) {
            const int k0 = (kt + 1) * 16;
            x0 = *(const float4*)(Xp0 + k0);
            x1 = *(const float4*)(Xp1 + k0);
            w0 = *(const float4*)(Wp0 + k0);
            w1 = *(const float4*)(Wp1 + k0);
        }
        asm volatile("s_waitcnt lgkmcnt(0)" ::: "memory");
        __builtin_amdgcn_s_barrier();
        asm volatile("" ::: "memory");

#pragma unroll
        for (int k = 0; k < 16; ++k) {
            const float4 alo = *(const float4*)&Xs[cur][k][rg * 4];
            const float4 ahi = *(const float4*)&Xs[cur][k][64 + rg * 4];
            const float4 blo = *(const float4*)&Ws[cur][k][n8];
            const float4 bhi = *(const float4*)&Ws[cur][k][n8 + 4];
            const float a[8] = {alo.x, alo.y, alo.z, alo.w,
                                ahi.x, ahi.y, ahi.z, ahi.w};
            const float b[8] = {blo.x, blo.y, blo.z, blo.w,
                                bhi.x, bhi.y, bhi.z, bhi.w};
#pragma unroll
            for (int u = 0; u < 8; ++u)
#pragma unroll
                for (int v = 0; v < 8; ++v)
                    acc[u][v] = fmaf(a[u], b[v], acc[u][v]);
        }
    }

    // ---- fused row-normalization of k / m sections via LDS scratch ----
    __syncthreads();   // all tile compute done; LDS reusable
    float* scr = &Xs[0][0][0];   // 128 rows x 8 partials
    const bool sect = (colblk == 0) ? (cg < 8) : (cg >= 8);
    if (sect) {
#pragma unroll
        for (int u = 0; u < 8; ++u) {
            float p = 0.f;
#pragma unroll
            for (int v = 0; v < 8; ++v) p += acc[u][v] * acc[u][v];
            scr[(m8 + u) * 8 + (cg & 7)] = p;
        }
    }
    __syncthreads();
    if (sect) {
#pragma unroll
        for (int u = 0; u < 8; ++u) {
            float s = 0.f;
#pragma unroll
            for (int j = 0; j < 8; ++j) s += scr[(m8 + u) * 8 + j];
            const float inv = __builtin_amdgcn_rcpf(sqrtf(s) + 1e-6f);
#pragma unroll
            for (int v = 0; v < 8; ++v) acc[u][v] *= inv;
        }
    }

#pragma unroll
    for (int u = 0; u < 8; ++u) {
        float* Cp = P + (long)(row0 + m8 + u) * PC + col0 + n8;
        *(float4*)(Cp)     = make_float4(acc[u][0], acc[u][1], acc[u][2], acc[u][3]);
        *(float4*)(Cp + 4) = make_float4(acc[u][4], acc[u][5], acc[u][6], acc[u][7]);
    }
}

// ---------------- Recurrent gated scan (barrier-free, 32 lanes/row) ----------
// 4096 (batch,row) sequences, independent given pre-normalized kn/mn.
// Wave: 2 rows, 32 lanes/row, 2 cols/lane -> 2048 waves. No LDS/barriers.
// Reductions batched into 2 phases: {S.k, M.k, M.m} (old state) then
// {S.m, S.q} (new S) -- 5 reductions, each 4 DPP + 1 swizzle.
__global__ __launch_bounds__(256) void gate_scan(
    const float* __restrict__ P,    // [T, B, 256] = [kn | v | q | mn]
    const float* __restrict__ S0,   // [B, 64, 64]
    const float* __restrict__ M0,
    const float* __restrict__ B_S,  // [64, 64]
    const float* __restrict__ B_M,
    float* __restrict__ out)        // [T*B*64] ++ [B*4096] ++ [B*4096]
{
    const int bid  = blockIdx.x;            // 0..511
    const int grp  = bid >> 3;
    const int b    = (bid & 7) * 8 + (grp >> 3);   // batch 0..63
    const int sub  = grp & 7;                      // block-within-batch
    const int w    = threadIdx.x >> 6;
    const int lane = threadIdx.x & 63;
    const int half = lane >> 5;
    const int li   = lane & 31;
    const int j0   = li * 2;                       // owned columns j0, j0+1
    const int r    = sub * 8 + w * 2 + half;       // matrix row 0..63

    float2 S2, M2, BS2, BM2;
    S2  = *(const float2*)(S0  + (long)b * 4096 + r * 64 + j0);
    M2  = *(const float2*)(M0  + (long)b * 4096 + r * 64 + j0);
    BS2 = *(const float2*)(B_S + r * 64 + j0);
    BM2 = *(const float2*)(B_M + r * 64 + j0);

    const float* Pb = P + (long)b * PC;
    const long   st = (long)BB * PC;    // per-step stride (floats)

    float2 kn = *(const float2*)(Pb + j0);
    float2 q2 = *(const float2*)(Pb + 128 + j0);
    float2 mn = *(const float2*)(Pb + 192 + j0);
    float  vv = Pb[64 + r];

    for (int t = 0; t < TT; ++t) {
        const long nb = (long)((t + 1 < TT) ? t + 1 : t) * st;
        const float2 knn = *(const float2*)(Pb + nb + j0);
        const float2 qn  = *(const float2*)(Pb + nb + 128 + j0);
        const float2 mnn = *(const float2*)(Pb + nb + 192 + j0);
        const float  vvn = Pb[nb + 64 + r];

        // ---- phase 1: three dots on OLD S, OLD M (independent chains) ----
        float sk = fmaf(S2.y, kn.y, S2.x * kn.x);
        float mk = fmaf(M2.y, kn.y, M2.x * kn.x);
        float mv = fmaf(M2.y, mn.y, M2.x * mn.x);
        sk = red32(sk);
        mk = red32(mk);
        mv = red32(mv);
        const float sd = vv - sk;              // s_delta[r]

        // S update (gate from old M)
        {
            const float g0 = fast_sigmoid(fmaf(mk, kn.x, M2.x + BS2.x));
            const float g1 = fast_sigmoid(fmaf(mk, kn.y, M2.y + BS2.y));
            S2.x = fmaf(g0, S2.x, sd * kn.x);
            S2.y = fmaf(g1, S2.y, sd * kn.y);
        }

        // ---- phase 2: two dots on NEW S ----
        float sm = fmaf(S2.y, mn.y, S2.x * mn.x);
        float sq = fmaf(S2.y, q2.y, S2.x * q2.x);
        sm = red32(sm);
        sq = red32(sq);
        const float md = sd - mv;              // m_delta[r]

        // M update (gate from new S)
        {
            const float g0 = fast_sigmoid(fmaf(sm, mn.x, S2.x + BM2.x));
            const float g1 = fast_sigmoid(fmaf(sm, mn.y, S2.y + BM2.y));
            M2.x = fmaf(g0, M2.x, md * mn.x);
            M2.y = fmaf(g1, M2.y, md * mn.y);
        }

        // readout: Sq * silu(Sq)
        if (li == 0)
            out[((long)t * BB + b) * NN + r] = sq * sq * fast_sigmoid(sq);

        kn = knn; q2 = qn; mn = mnn; vv = vvn;
    }

    float* So = out + (long)TT * BB * NN + (long)b * 4096 + r * 64 + j0;
    float* Mo = So + (long)BB * 4096;
    *(float2*)So = S2;
    *(float2*)Mo = M2;
}

extern "C" void kernel_launch(void* const* d_in, const int* in_sizes, int n_in,
                              void* d_out, int out_size, void* d_ws, size_t ws_size,
                              hipStream_t stream) {
    const float* x    = (const float*)d_in[0];  // [512,64,1024]
    const float* S0   = (const float*)d_in[1];  // [64,64,64]
    const float* M0   = (const float*)d_in[2];
    const float* W    = (const float*)d_in[3];  // [256,1024]
    const float* B_S  = (const float*)d_in[4];  // [64,64]
    const float* B_M  = (const float*)d_in[5];
    float* out  = (float*)d_out;
    float* proj = (float*)d_ws;                 // 512*64*256*4 = 32 MB

    proj_gemm<<<512, 256, 0, stream>>>(x, W, proj);
    gate_scan<<<512, 256, 0, stream>>>(proj, S0, M0, B_S, B_M, out);
}

// Round 10
// 537.506 us; speedup vs baseline: 1.3025x; 1.0579x over previous
//
#include <hip/hip_runtime.h>
#include <math.h>

#define TT 512
#define BB 64
#define DD 1024
#define NN 64
#define PC 256   // 4*NN projection columns

__device__ __forceinline__ float fast_sigmoid(float x) {
    float e = __builtin_amdgcn_exp2f(x * -1.442695041f);
    return __builtin_amdgcn_rcpf(1.0f + e);
}

template<int C>
__device__ __forceinline__ float dpp_mov(float x) {
    return __int_as_float(__builtin_amdgcn_update_dpp(
        0, __float_as_int(x), C, 0xF, 0xF, true));
}
template<int P>
__device__ __forceinline__ float swz(float x) {
    return __int_as_float(__builtin_amdgcn_ds_swizzle(__float_as_int(x), P));
}
// Butterfly sum across each 32-lane half; only ONE LDS-pipe op (xor16).
__device__ __forceinline__ float red32(float x) {
    x += dpp_mov<0xB1>(x);     // xor 1
    x += dpp_mov<0x4E>(x);     // xor 2
    x += dpp_mov<0x140>(x);    // row_mirror
    x += dpp_mov<0x128>(x);    // row_ror:8
    x += swz<0x401F>(x);       // xor 16
    return x;
}

// ---------------- Projection GEMM (fp32, 128x128 tile, 8x8/thread) ----------
// (unchanged from round 5/8 -- measured neutral-to-positive, < 240 us)
__global__ __launch_bounds__(256, 2) void proj_gemm(
    const float* __restrict__ X,
    const float* __restrict__ W,
    float* __restrict__ P)
{
    __shared__ float Xs[2][16][132];
    __shared__ float Ws[2][16][132];

    const int t      = threadIdx.x;
    const int rowblk = blockIdx.x >> 1;
    const int colblk = blockIdx.x & 1;
    const int row0   = rowblk * 128;
    const int col0   = colblk * 128;
    const int rg     = t & 15;       // row group (8 rows)
    const int cg     = t >> 4;       // col group (8 cols)
    const int m8     = rg * 8;
    const int n8     = cg * 8;

    const int lrow0 = t >> 2;
    const int lrow1 = lrow0 + 64;
    const int lkg   = (t & 3) * 4;

    const float* Xp0 = X + (long)(row0 + lrow0) * DD + lkg;
    const float* Xp1 = X + (long)(row0 + lrow1) * DD + lkg;
    const float* Wp0 = W + (long)(col0 + lrow0) * DD + lkg;
    const float* Wp1 = W + (long)(col0 + lrow1) * DD + lkg;

    const int pc0 = ((lrow0 & 4) << 4) + ((lrow0 >> 3) << 2) + (lrow0 & 3);
    const int pc1 = ((lrow1 & 4) << 4) + ((lrow1 >> 3) << 2) + (lrow1 & 3);

    float acc[8][8];
#pragma unroll
    for (int u = 0; u < 8; ++u)
#pragma unroll
        for (int v = 0; v < 8; ++v) acc[u][v] = 0.f;

    float4 x0 = *(const float4*)(Xp0);
    float4 x1 = *(const float4*)(Xp1);
    float4 w0 = *(const float4*)(Wp0);
    float4 w1 = *(const float4*)(Wp1);

    for (int kt = 0; kt < 64; ++kt) {
        const int cur = kt & 1;
        {
            const float xa0[4] = {x0.x, x0.y, x0.z, x0.w};
            const float xa1[4] = {x1.x, x1.y, x1.z, x1.w};
            const float wa0[4] = {w0.x, w0.y, w0.z, w0.w};
            const float wa1[4] = {w1.x, w1.y, w1.z, w1.w};
#pragma unroll
            for (int f = 0; f < 4; ++f) {
                Xs[cur][lkg + f][pc0]   = xa0[f];
                Xs[cur][lkg + f][pc1]   = xa1[f];
                Ws[cur][lkg + f][lrow0] = wa0[f];
                Ws[cur][lkg + f][lrow1] = wa1[f];
            }
        }
        if (kt < 63) {
            const int k0 = (kt + 1) * 16;
            x0 = *(const float4*)(Xp0 + k0);
            x1 = *(const float4*)(Xp1 + k0);
            w0 = *(const float4*)(Wp0 + k0);
            w1 = *(const float4*)(Wp1 + k0);
        }
        asm volatile("s_waitcnt lgkmcnt(0)" ::: "memory");
        __builtin_amdgcn_s_barrier();
        asm volatile("" ::: "memory");

#pragma unroll
        for (int k = 0; k < 16; ++k) {
            const float4 alo = *(const float4*)&Xs[cur][k][rg * 4];
            const float4 ahi = *(const float4*)&Xs[cur][k][64 + rg * 4];
            const float4 blo = *(const float4*)&Ws[cur][k][n8];
            const float4 bhi = *(const float4*)&Ws[cur][k][n8 + 4];
            const float a[8] = {alo.x, alo.y, alo.z, alo.w,
                                ahi.x, ahi.y, ahi.z, ahi.w};
            const float b[8] = {blo.x, blo.y, blo.z, blo.w,
                                bhi.x, bhi.y, bhi.z, bhi.w};
#pragma unroll
            for (int u = 0; u < 8; ++u)
#pragma unroll
                for (int v = 0; v < 8; ++v)
                    acc[u][v] = fmaf(a[u], b[v], acc[u][v]);
        }
    }

    __syncthreads();
    float* scr = &Xs[0][0][0];
    const bool sect = (colblk == 0) ? (cg < 8) : (cg >= 8);
    if (sect) {
#pragma unroll
        for (int u = 0; u < 8; ++u) {
            float p = 0.f;
#pragma unroll
            for (int v = 0; v < 8; ++v) p += acc[u][v] * acc[u][v];
            scr[(m8 + u) * 8 + (cg & 7)] = p;
        }
    }
    __syncthreads();
    if (sect) {
#pragma unroll
        for (int u = 0; u < 8; ++u) {
            float s = 0.f;
#pragma unroll
            for (int j = 0; j < 8; ++j) s += scr[(m8 + u) * 8 + j];
            const float inv = __builtin_amdgcn_rcpf(sqrtf(s) + 1e-6f);
#pragma unroll
            for (int v = 0; v < 8; ++v) acc[u][v] *= inv;
        }
    }

#pragma unroll
    for (int u = 0; u < 8; ++u) {
        float* Cp = P + (long)(row0 + m8 + u) * PC + col0 + n8;
        *(float4*)(Cp)     = make_float4(acc[u][0], acc[u][1], acc[u][2], acc[u][3]);
        *(float4*)(Cp + 4) = make_float4(acc[u][4], acc[u][5], acc[u][6], acc[u][7]);
    }
}

// ---------------- Recurrent gated scan (barrier-free, 32 lanes/row) ----------
// Same math/layout as round 8 (passing, absmax 1.0). Changes are pure
// addressing: 32-bit marching element offsets off the uniform base (one add
// per pointer per step; +128/+192 fold into load immediate offsets),
// hoisted writer predicate, unroll-2 to kill cur<-next copies.
__global__ __launch_bounds__(256) void gate_scan(
    const float* __restrict__ P,    // [T, B, 256] = [kn | v | q | mn]
    const float* __restrict__ S0,   // [B, 64, 64]
    const float* __restrict__ M0,
    const float* __restrict__ B_S,  // [64, 64]
    const float* __restrict__ B_M,
    float* __restrict__ out)        // [T*B*64] ++ [B*4096] ++ [B*4096]
{
    const int bid  = blockIdx.x;            // 0..511
    const int grp  = bid >> 3;
    const int b    = (bid & 7) * 8 + (grp >> 3);   // batch 0..63
    const int sub  = grp & 7;                      // block-within-batch
    const int w    = threadIdx.x >> 6;
    const int lane = threadIdx.x & 63;
    const int half = lane >> 5;
    const int li   = lane & 31;
    const int j0   = li * 2;                       // owned columns j0, j0+1
    const int r    = sub * 8 + w * 2 + half;       // matrix row 0..63

    float2 S2, M2, BS2, BM2;
    S2  = *(const float2*)(S0  + (long)b * 4096 + r * 64 + j0);
    M2  = *(const float2*)(M0  + (long)b * 4096 + r * 64 + j0);
    BS2 = *(const float2*)(B_S + r * 64 + j0);
    BM2 = *(const float2*)(B_M + r * 64 + j0);

    const unsigned STEP = (unsigned)BB * PC;   // 16384 floats/step
    unsigned koff = (unsigned)b * PC + j0;     // k at +0, q at +128, m at +192
    unsigned voff = (unsigned)b * PC + 64 + r;
    unsigned ooff = (unsigned)b * NN + r;      // advances BB*NN per step
    const bool writer = (li == 0);

    float2 kn = *(const float2*)(P + koff);
    float2 q2 = *(const float2*)(P + koff + 128);
    float2 mn = *(const float2*)(P + koff + 192);
    float  vv = P[voff];

#pragma unroll 2
    for (int t = 0; t < TT; ++t) {
        // prefetch next step (select folds to SALU; offsets stay 32-bit)
        const unsigned kof2 = koff + ((t + 1 < TT) ? STEP : 0u);
        const unsigned vof2 = voff + ((t + 1 < TT) ? STEP : 0u);
        const float2 knn = *(const float2*)(P + kof2);
        const float2 qn  = *(const float2*)(P + kof2 + 128);
        const float2 mnn = *(const float2*)(P + kof2 + 192);
        const float  vvn = P[vof2];
        koff = kof2; voff = vof2;

        // ---- phase 1: three dots on OLD S, OLD M (independent chains) ----
        float sk = fmaf(S2.y, kn.y, S2.x * kn.x);
        float mk = fmaf(M2.y, kn.y, M2.x * kn.x);
        float mv = fmaf(M2.y, mn.y, M2.x * mn.x);
        sk = red32(sk);
        mk = red32(mk);
        mv = red32(mv);
        const float sd = vv - sk;              // s_delta[r]

        // S update (gate from old M)
        {
            const float g0 = fast_sigmoid(fmaf(mk, kn.x, M2.x + BS2.x));
            const float g1 = fast_sigmoid(fmaf(mk, kn.y, M2.y + BS2.y));
            S2.x = fmaf(g0, S2.x, sd * kn.x);
            S2.y = fmaf(g1, S2.y, sd * kn.y);
        }

        // ---- phase 2: two dots on NEW S ----
        float sm = fmaf(S2.y, mn.y, S2.x * mn.x);
        float sq = fmaf(S2.y, q2.y, S2.x * q2.x);
        sm = red32(sm);
        sq = red32(sq);
        const float md = sd - mv;              // m_delta[r]

        // M update (gate from new S)
        {
            const float g0 = fast_sigmoid(fmaf(sm, mn.x, S2.x + BM2.x));
            const float g1 = fast_sigmoid(fmaf(sm, mn.y, S2.y + BM2.y));
            M2.x = fmaf(g0, M2.x, md * mn.x);
            M2.y = fmaf(g1, M2.y, md * mn.y);
        }

        // readout: Sq * silu(Sq)
        if (writer) out[ooff] = sq * sq * fast_sigmoid(sq);
        ooff += (unsigned)BB * NN;

        kn = knn; q2 = qn; mn = mnn; vv = vvn;
    }

    float* So = out + (long)TT * BB * NN + (long)b * 4096 + r * 64 + j0;
    float* Mo = So + (long)BB * 4096;
    *(float2*)So = S2;
    *(float2*)Mo = M2;
}

extern "C" void kernel_launch(void* const* d_in, const int* in_sizes, int n_in,
                              void* d_out, int out_size, void* d_ws, size_t ws_size,
                              hipStream_t stream) {
    const float* x    = (const float*)d_in[0];  // [512,64,1024]
    const float* S0   = (const float*)d_in[1];  // [64,64,64]
    const float* M0   = (const float*)d_in[2];
    const float* W    = (const float*)d_in[3];  // [256,1024]
    const float* B_S  = (const float*)d_in[4];  // [64,64]
    const float* B_M  = (const float*)d_in[5];
    float* out  = (float*)d_out;
    float* proj = (float*)d_ws;                 // 512*64*256*4 = 32 MB

    proj_gemm<<<512, 256, 0, stream>>>(x, W, proj);
    gate_scan<<<512, 256, 0, stream>>>(proj, S0, M0, B_S, B_M, out);
}